// Round 6
// baseline (376.161 us; speedup 1.0000x reference)
//
#include <hip/hip_runtime.h>
#include <hip/hip_bf16.h>

#define N_NODES  100000
#define N_EDGES  3200000
#define N_GRAPHS 1000
#define IN_DIM   10
#define HID      20
#define BN_EPS   1e-5f

#define BSH   7                              // 128-node buckets
#define NB    ((N_NODES + 127) / 128)        // 782 buckets
#define CAP   4608                           // per-bucket capacity (mean 4096 + 8 sigma)
#define FB    512                            // fill blocks
#define FT    512                            // fill threads
#define FCHUNK ((N_EDGES + FB - 1) / FB)     // 6250 edges/block
#define NBG   ((N_NODES + 31) / 32)          // 3125 gather blocks (32 nodes, 8 subs)

// ---------------------------------------------------------------------------
// Fill into fixed-capacity buckets. Pass 1: LDS-stash dst + LDS count.
// Block reserves per-bucket runs via global cursor; pass 2 writes runs densely.
// packed = src | (dst&127)<<24 at packed[b*CAP + ...]
// ---------------------------------------------------------------------------
__global__ __launch_bounds__(FT) void fill_direct(const int* __restrict__ src,
                                                  const int* __restrict__ dst,
                                                  int* __restrict__ bcur,
                                                  unsigned* __restrict__ packed) {
    __shared__ int sdst[FCHUNK];   // 25,000 B
    __shared__ int cnt[NB];
    __shared__ int base[NB];
    int t = threadIdx.x;
    for (int i = t; i < NB; i += FT) cnt[i] = 0;
    __syncthreads();
    int e0 = blockIdx.x * FCHUNK;
    int e1 = min(e0 + FCHUNK, N_EDGES);
    int m = e1 - e0;
    for (int i = t; i < m; i += FT) {
        int d = dst[e0 + i];
        sdst[i] = d;
        atomicAdd(&cnt[d >> BSH], 1);
    }
    __syncthreads();
    for (int i = t; i < NB; i += FT) {
        int c = cnt[i];
        base[i] = c ? atomicAdd(&bcur[i], c) : 0;
        cnt[i] = 0;
    }
    __syncthreads();
    for (int i = t; i < m; i += FT) {
        int d = sdst[i];
        int b = d >> BSH;
        int r = atomicAdd(&cnt[b], 1);
        packed[(size_t)b * CAP + base[b] + r] =
            (unsigned)src[e0 + i] | ((unsigned)(d & 127) << 24);
    }
}

// ---------------------------------------------------------------------------
// Exclusive scan of bucket counts -> compact csr offsets
// ---------------------------------------------------------------------------
__global__ void scan_buckets(const int* __restrict__ bcur, int* __restrict__ off) {
    __shared__ int lds[1024];
    int t = threadIdx.x;
    int v = (t < NB) ? bcur[t] : 0;
    int val = v;
    lds[t] = val; __syncthreads();
    for (int o = 1; o < 1024; o <<= 1) {
        int a = (t >= o) ? lds[t - o] : 0;
        __syncthreads();
        val += a; lds[t] = val;
        __syncthreads();
    }
    if (t < NB) off[t] = val - v;
    if (t == 0) off[NB] = N_EDGES;
}

// ---------------------------------------------------------------------------
// Per-bucket counting sort by 7-bit local dst -> compact node-exact CSR + rp
// ---------------------------------------------------------------------------
__global__ __launch_bounds__(512) void sort_bucket(const unsigned* __restrict__ packed,
                                                   const int* __restrict__ bcnt,
                                                   const int* __restrict__ off,
                                                   int* __restrict__ csr,
                                                   int* __restrict__ rp) {
    __shared__ unsigned ebuf[CAP];     // 18,432 B
    __shared__ int cnt[128];
    __shared__ int cur[128];
    int b = blockIdx.x, t = threadIdx.x;
    int m = bcnt[b];
    int o = off[b];
    const unsigned* pb = packed + (size_t)b * CAP;
    for (int i = t; i < m; i += 512) ebuf[i] = pb[i];
    if (t < 128) cnt[t] = 0;
    __syncthreads();
    for (int i = t; i < m; i += 512) atomicAdd(&cnt[ebuf[i] >> 24], 1);
    __syncthreads();
    int v = 0, val = 0;
    if (t < 128) { v = cnt[t]; val = v; cur[t] = val; }
    __syncthreads();
    for (int ofs = 1; ofs < 128; ofs <<= 1) {
        int add = (t < 128 && t >= ofs) ? cur[t - ofs] : 0;
        __syncthreads();
        if (t < 128) { val += add; cur[t] = val; }
        __syncthreads();
    }
    if (t < 128) {
        int node = b * 128 + t;
        if (node <= N_NODES) rp[node] = o + (val - v);
        cur[t] = val - v;
    }
    __syncthreads();
    for (int i = t; i < m; i += 512) {
        unsigned p = ebuf[i];
        int l = p >> 24;
        int pos = atomicAdd(&cur[l], 1);
        csr[o + pos] = (int)(p & 0xFFFFFFu);
    }
}

// ---------------------------------------------------------------------------
// Gather (+fused prev-layer BN+ReLU on loads) + MLP + BN partials.
// 8 threads per node, 4-row staged unroll, butterfly merge; subs 0-3 compute
// 5 output channels each; partials stat-major [2*HID][NBG].
// ---------------------------------------------------------------------------
template<int DIN, bool BN>
__global__ __launch_bounds__(256) void gather_mlp8(
        const float* __restrict__ h,
        const int* __restrict__ rp, const int* __restrict__ csr,
        const float* __restrict__ W,    // [DIN][HID]
        const float* __restrict__ bias,
        const float* __restrict__ ssin, // [2*HID] prev-layer scale/shift
        float* __restrict__ hpre,       // [N][HID]
        float* __restrict__ partials)   // [2*HID][NBG]
{
    __shared__ float sW[DIN * HID];
    __shared__ float sb[HID];
    __shared__ float sss[2 * HID];
    __shared__ float red[4][2 * HID];
    int t = threadIdx.x;
    for (int i = t; i < DIN * HID; i += 256) sW[i] = W[i];
    if (t < HID) sb[t] = bias[t];
    if constexpr (BN) { if (t < 2 * HID) sss[t] = ssin[t]; }
    __syncthreads();

    int node = blockIdx.x * 32 + (t >> 3);
    int sub  = t & 7;
    float u[DIN];
#pragma unroll
    for (int k = 0; k < DIN; k++) u[k] = 0.0f;

    auto acc4 = [&](float4 a, int q) {
        float v0 = a.x, v1 = a.y, v2 = a.z, v3 = a.w;
        if constexpr (BN) {
            v0 = fmaxf(fmaf(v0, sss[4*q+0], sss[HID+4*q+0]), 0.f);
            v1 = fmaxf(fmaf(v1, sss[4*q+1], sss[HID+4*q+1]), 0.f);
            v2 = fmaxf(fmaf(v2, sss[4*q+2], sss[HID+4*q+2]), 0.f);
            v3 = fmaxf(fmaf(v3, sss[4*q+3], sss[HID+4*q+3]), 0.f);
        }
        u[4*q] += v0; u[4*q+1] += v1; u[4*q+2] += v2; u[4*q+3] += v3;
    };

    if (node < N_NODES) {
        int e0 = rp[node], e1 = rp[node + 1];
        if (sub == 0) {   // self term
            if constexpr (DIN == 20) {
                const float4* hv = (const float4*)(h + (size_t)node * 20);
#pragma unroll
                for (int q = 0; q < 5; q++) acc4(hv[q], q);
            } else {
                const float2* hv = (const float2*)(h + (size_t)node * DIN);
#pragma unroll
                for (int q = 0; q < 5; q++) {
                    float2 a = hv[q];
                    u[2*q] += a.x; u[2*q+1] += a.y;
                }
            }
        }
        int e = e0 + sub;
        if constexpr (DIN == 20) {
            for (; e + 24 < e1; e += 32) {   // 4 rows staged: 20 loads in flight
                int s0 = csr[e], s1 = csr[e + 8], s2 = csr[e + 16], s3 = csr[e + 24];
                const float4* a0 = (const float4*)(h + (size_t)s0 * 20);
                const float4* a1 = (const float4*)(h + (size_t)s1 * 20);
                const float4* a2 = (const float4*)(h + (size_t)s2 * 20);
                const float4* a3 = (const float4*)(h + (size_t)s3 * 20);
                float4 r0[5], r1[5], r2[5], r3[5];
#pragma unroll
                for (int q = 0; q < 5; q++) r0[q] = a0[q];
#pragma unroll
                for (int q = 0; q < 5; q++) r1[q] = a1[q];
#pragma unroll
                for (int q = 0; q < 5; q++) r2[q] = a2[q];
#pragma unroll
                for (int q = 0; q < 5; q++) r3[q] = a3[q];
#pragma unroll
                for (int q = 0; q < 5; q++) {
                    acc4(r0[q], q); acc4(r1[q], q); acc4(r2[q], q); acc4(r3[q], q);
                }
            }
            for (; e + 8 < e1; e += 16) {    // 2-row tail
                int s0 = csr[e], s1 = csr[e + 8];
                const float4* a0 = (const float4*)(h + (size_t)s0 * 20);
                const float4* a1 = (const float4*)(h + (size_t)s1 * 20);
                float4 r0[5], r1[5];
#pragma unroll
                for (int q = 0; q < 5; q++) r0[q] = a0[q];
#pragma unroll
                for (int q = 0; q < 5; q++) r1[q] = a1[q];
#pragma unroll
                for (int q = 0; q < 5; q++) { acc4(r0[q], q); acc4(r1[q], q); }
            }
            if (e < e1) {
                const float4* a0 = (const float4*)(h + (size_t)csr[e] * 20);
#pragma unroll
                for (int q = 0; q < 5; q++) acc4(a0[q], q);
            }
        } else {
            for (; e + 24 < e1; e += 32) {
                int s0 = csr[e], s1 = csr[e + 8], s2 = csr[e + 16], s3 = csr[e + 24];
                const float2* a0 = (const float2*)(h + (size_t)s0 * DIN);
                const float2* a1 = (const float2*)(h + (size_t)s1 * DIN);
                const float2* a2 = (const float2*)(h + (size_t)s2 * DIN);
                const float2* a3 = (const float2*)(h + (size_t)s3 * DIN);
                float2 r0[5], r1[5], r2[5], r3[5];
#pragma unroll
                for (int q = 0; q < 5; q++) r0[q] = a0[q];
#pragma unroll
                for (int q = 0; q < 5; q++) r1[q] = a1[q];
#pragma unroll
                for (int q = 0; q < 5; q++) r2[q] = a2[q];
#pragma unroll
                for (int q = 0; q < 5; q++) r3[q] = a3[q];
#pragma unroll
                for (int q = 0; q < 5; q++) {
                    u[2*q]   += r0[q].x + r1[q].x + r2[q].x + r3[q].x;
                    u[2*q+1] += r0[q].y + r1[q].y + r2[q].y + r3[q].y;
                }
            }
            for (; e < e1; e += 8) {
                const float2* a0 = (const float2*)(h + (size_t)csr[e] * DIN);
#pragma unroll
                for (int q = 0; q < 5; q++) {
                    float2 x0 = a0[q];
                    u[2*q] += x0.x; u[2*q+1] += x0.y;
                }
            }
        }
    }

    // merge 8 sub-accumulators
#pragma unroll
    for (int k = 0; k < DIN; k++) {
        u[k] += __shfl_xor(u[k], 1);
        u[k] += __shfl_xor(u[k], 2);
        u[k] += __shfl_xor(u[k], 4);
    }

    // MLP: subs 0-3 compute channels [sub*5, sub*5+5)
    const int c0 = (sub & 3) * 5;
    float out[5];
#pragma unroll
    for (int j = 0; j < 5; j++) out[j] = sb[c0 + j];
#pragma unroll
    for (int k = 0; k < DIN; k++) {
        float uk = u[k];
#pragma unroll
        for (int j = 0; j < 5; j++)
            out[j] = fmaf(uk, sW[k * HID + c0 + j], out[j]);
    }
    bool live = (node < N_NODES) && (sub < 4);
    if (live) {
        float* op = hpre + (size_t)node * HID + c0;
#pragma unroll
        for (int j = 0; j < 5; j++) op[j] = out[j];
    }

    // BN partials
    float msk = live ? 1.0f : 0.0f;
    float s1[5], s2[5];
#pragma unroll
    for (int j = 0; j < 5; j++) {
        float o = out[j] * msk;
        s1[j] = o; s2[j] = o * out[j];
    }
    for (int o = 8; o < 64; o <<= 1) {
#pragma unroll
        for (int j = 0; j < 5; j++) {
            s1[j] += __shfl_down(s1[j], o);
            s2[j] += __shfl_down(s2[j], o);
        }
    }
    int lane = t & 63, wave = t >> 6;
    if (lane < 4) {
#pragma unroll
        for (int j = 0; j < 5; j++) {
            red[wave][lane * 5 + j]       = s1[j];
            red[wave][HID + lane * 5 + j] = s2[j];
        }
    }
    __syncthreads();
    if (t < 2 * HID)
        partials[(size_t)t * NBG + blockIdx.x] =
            red[0][t] + red[1][t] + red[2][t] + red[3][t];
}

// ---------------------------------------------------------------------------
// BN prep: 20 blocks, block c reduces stat rows c and c+20 (coalesced), f64
// ---------------------------------------------------------------------------
__global__ __launch_bounds__(256) void bn_prep(const float* __restrict__ partials,
                                               const float* __restrict__ g,
                                               const float* __restrict__ beta,
                                               float* __restrict__ ss) {
    int c = blockIdx.x, t = threadIdx.x;
    double a1 = 0.0, a2 = 0.0;
    for (int i = t; i < NBG; i += 256) {
        a1 += (double)partials[(size_t)c * NBG + i];
        a2 += (double)partials[(size_t)(c + HID) * NBG + i];
    }
    for (int o = 32; o; o >>= 1) {
        a1 += __shfl_down(a1, o);
        a2 += __shfl_down(a2, o);
    }
    __shared__ double r1[4], r2[4];
    int lane = t & 63, wave = t >> 6;
    if (lane == 0) { r1[wave] = a1; r2[wave] = a2; }
    __syncthreads();
    if (t == 0) {
        double su = r1[0] + r1[1] + r1[2] + r1[3];
        double sq = r2[0] + r2[1] + r2[2] + r2[3];
        double mu  = su / (double)N_NODES;
        double var = sq / (double)N_NODES - mu * mu;
        float sc = g[c] * (float)(1.0 / sqrt(var + (double)BN_EPS));
        ss[c]       = sc;
        ss[HID + c] = beta[c] - (float)mu * sc;
    }
}

// ---------------------------------------------------------------------------
// graph_ptr from sorted batch (handles empty graphs)
// ---------------------------------------------------------------------------
__global__ void gptr_kernel(const int* __restrict__ batch, int* __restrict__ gptr) {
    int n = blockIdx.x * blockDim.x + threadIdx.x;
    if (n >= N_NODES) return;
    int g = batch[n];
    int gp = (n == 0) ? -1 : batch[n - 1];
    for (int q = gp + 1; q <= g; q++) gptr[q] = n;
    if (n == N_NODES - 1)
        for (int q = g + 1; q <= N_GRAPHS; q++) gptr[q] = N_NODES;
}

// ---------------------------------------------------------------------------
// Pool (+fused BN3+ReLU) + FC, block per graph
// ---------------------------------------------------------------------------
__global__ __launch_bounds__(256) void pool_fc(const float* __restrict__ h,
                                               const int* __restrict__ gptr,
                                               const float* __restrict__ ss,
                                               const float* __restrict__ fcW,
                                               const float* __restrict__ fcb,
                                               float* __restrict__ out) {
    __shared__ float red[12][HID];
    __shared__ float sss[2 * HID];
    __shared__ float pl[HID];
    int g = blockIdx.x, t = threadIdx.x;
    if (t < 2 * HID) sss[t] = ss[t];
    __syncthreads();
    int n0 = gptr[g], n1 = gptr[g + 1];
    if (t < 240) {
        int c = t % HID, grp = t / HID;
        float s = 0.0f;
        for (int n = n0 + grp; n < n1; n += 12) {
            float v = fmaf(h[(size_t)n * HID + c], sss[c], sss[HID + c]);
            s += v > 0.0f ? v : 0.0f;
        }
        red[grp][c] = s;
    }
    __syncthreads();
    if (t < HID) {
        float a = 0.0f;
#pragma unroll
        for (int q = 0; q < 12; q++) a += red[q][t];
        pl[t] = a;
    }
    __syncthreads();
    if (t < 2) {
        float o = fcb[t];
#pragma unroll
        for (int k = 0; k < HID; k++) o = fmaf(pl[k], fcW[k * 2 + t], o);
        out[g * 2 + t] = o;
    }
}

extern "C" void kernel_launch(void* const* d_in, const int* in_sizes, int n_in,
                              void* d_out, int out_size, void* d_ws, size_t ws_size,
                              hipStream_t stream) {
    const float* x     = (const float*)d_in[0];
    const int*   eidx  = (const int*)d_in[1];
    const int*   batch = (const int*)d_in[2];
    const float* W1 = (const float*)d_in[3];
    const float* b1 = (const float*)d_in[4];
    const float* g1 = (const float*)d_in[5];
    const float* be1 = (const float*)d_in[6];
    const float* W2 = (const float*)d_in[7];
    const float* b2 = (const float*)d_in[8];
    const float* g2 = (const float*)d_in[9];
    const float* be2 = (const float*)d_in[10];
    const float* W3 = (const float*)d_in[11];
    const float* b3 = (const float*)d_in[12];
    const float* g3 = (const float*)d_in[13];
    const float* be3 = (const float*)d_in[14];
    const float* fcW = (const float*)d_in[15];
    const float* fcb = (const float*)d_in[16];
    float* out = (float*)d_out;

    const int* src = eidx;
    const int* dst = eidx + N_EDGES;

    // workspace layout (bytes). packed (build-only, 14.4MB fixed-cap) aliases
    // hA/hB (16MB): build completes before any gather writes hA/hB.
    char* ws = (char*)d_ws;
    float* hA      = (float*)(ws + 0);               // 8,000,000
    float* hB      = (float*)(ws + 8000000);         // 8,000,000
    unsigned* packed = (unsigned*)(ws + 0);          // NB*CAP*4 = 14,411,776 (alias)
    int*   csr     = (int*)(ws + 16000000);          // 12,800,000
    int*   rp      = (int*)(ws + 28800000);          // 400,004
    int*   off     = (int*)(ws + 29200128);          // 3,132
    int*   bcur    = (int*)(ws + 29203328);          // 3,128
    float* partials= (float*)(ws + 29209728);        // 40*3125*4 = 500,000
    float* ss1     = (float*)(ws + 29709728);        // 160
    float* ss2     = (float*)(ws + 29709888);        // 160
    float* ss3     = (float*)(ws + 29710048);        // 160
    int*   gptr    = (int*)(ws + 29710208);          // 4,004

    const int BLK = 256;

    // ---- sorted node-exact CSR (built once, reused by all 3 layers) ----
    hipMemsetAsync(bcur, 0, NB * sizeof(int), stream);
    fill_direct<<<FB, FT, 0, stream>>>(src, dst, bcur, packed);
    scan_buckets<<<1, 1024, 0, stream>>>(bcur, off);
    sort_bucket<<<NB, 512, 0, stream>>>(packed, bcur, off, csr, rp);
    gptr_kernel<<<(N_NODES + BLK - 1) / BLK, BLK, 0, stream>>>(batch, gptr);

    // ---- layer 1 (DIN=10, no input BN) ----
    gather_mlp8<IN_DIM, false><<<NBG, BLK, 0, stream>>>(x, rp, csr, W1, b1, ss1, hA, partials);
    bn_prep<<<HID, BLK, 0, stream>>>(partials, g1, be1, ss1);

    // ---- layer 2 (DIN=20, fused BN1+ReLU on loads) ----
    gather_mlp8<HID, true><<<NBG, BLK, 0, stream>>>(hA, rp, csr, W2, b2, ss1, hB, partials);
    bn_prep<<<HID, BLK, 0, stream>>>(partials, g2, be2, ss2);

    // ---- layer 3 (DIN=20, fused BN2+ReLU on loads) ----
    gather_mlp8<HID, true><<<NBG, BLK, 0, stream>>>(hB, rp, csr, W3, b3, ss2, hA, partials);
    bn_prep<<<HID, BLK, 0, stream>>>(partials, g3, be3, ss3);

    // ---- pool (+BN3+ReLU) + FC ----
    pool_fc<<<N_GRAPHS, BLK, 0, stream>>>(hA, gptr, ss3, fcW, fcb, out);
}

// Round 7
// 340.248 us; speedup vs baseline: 1.1056x; 1.1056x over previous
//
#include <hip/hip_runtime.h>
#include <hip/hip_bf16.h>

#define N_NODES  100000
#define N_EDGES  3200000
#define N_GRAPHS 1000
#define IN_DIM   10
#define HID      20
#define BN_EPS   1e-5f

#define BSH   7                              // 128-node buckets
#define NB    ((N_NODES + 127) / 128)        // 782 buckets
#define CAP   4608                           // per-bucket capacity (mean 4096 + 8 sigma)
#define FB    512                            // fill blocks
#define FT    512                            // fill threads
#define FCHUNK ((N_EDGES + FB - 1) / FB)     // 6250 edges/block
#define NBG   ((N_NODES + 31) / 32)          // 3125 gather blocks (32 nodes, 8 subs)

// ---------------------------------------------------------------------------
// Fill into fixed-capacity buckets. Pass 1: LDS-stash dst + LDS count.
// Block reserves per-bucket runs via global cursor; pass 2 writes runs densely.
// packed = src | (dst&127)<<24 at packed[b*CAP + ...]
// ---------------------------------------------------------------------------
__global__ __launch_bounds__(FT) void fill_direct(const int* __restrict__ src,
                                                  const int* __restrict__ dst,
                                                  int* __restrict__ bcur,
                                                  unsigned* __restrict__ packed) {
    __shared__ int sdst[FCHUNK];   // 25,000 B
    __shared__ int cnt[NB];
    __shared__ int base[NB];
    int t = threadIdx.x;
    for (int i = t; i < NB; i += FT) cnt[i] = 0;
    __syncthreads();
    int e0 = blockIdx.x * FCHUNK;
    int e1 = min(e0 + FCHUNK, N_EDGES);
    int m = e1 - e0;
    for (int i = t; i < m; i += FT) {
        int d = dst[e0 + i];
        sdst[i] = d;
        atomicAdd(&cnt[d >> BSH], 1);
    }
    __syncthreads();
    for (int i = t; i < NB; i += FT) {
        int c = cnt[i];
        base[i] = c ? atomicAdd(&bcur[i], c) : 0;
        cnt[i] = 0;
    }
    __syncthreads();
    for (int i = t; i < m; i += FT) {
        int d = sdst[i];
        int b = d >> BSH;
        int r = atomicAdd(&cnt[b], 1);
        packed[(size_t)b * CAP + base[b] + r] =
            (unsigned)src[e0 + i] | ((unsigned)(d & 127) << 24);
    }
}

// ---------------------------------------------------------------------------
// Exclusive scan of bucket counts -> compact csr offsets
// ---------------------------------------------------------------------------
__global__ void scan_buckets(const int* __restrict__ bcur, int* __restrict__ off) {
    __shared__ int lds[1024];
    int t = threadIdx.x;
    int v = (t < NB) ? bcur[t] : 0;
    int val = v;
    lds[t] = val; __syncthreads();
    for (int o = 1; o < 1024; o <<= 1) {
        int a = (t >= o) ? lds[t - o] : 0;
        __syncthreads();
        val += a; lds[t] = val;
        __syncthreads();
    }
    if (t < NB) off[t] = val - v;
    if (t == 0) off[NB] = N_EDGES;
}

// ---------------------------------------------------------------------------
// Per-bucket counting sort by 7-bit local dst -> compact node-exact CSR + rp
// ---------------------------------------------------------------------------
__global__ __launch_bounds__(512) void sort_bucket(const unsigned* __restrict__ packed,
                                                   const int* __restrict__ bcnt,
                                                   const int* __restrict__ off,
                                                   int* __restrict__ csr,
                                                   int* __restrict__ rp) {
    __shared__ unsigned ebuf[CAP];     // 18,432 B
    __shared__ int cnt[128];
    __shared__ int cur[128];
    int b = blockIdx.x, t = threadIdx.x;
    int m = bcnt[b];
    int o = off[b];
    const unsigned* pb = packed + (size_t)b * CAP;
    for (int i = t; i < m; i += 512) ebuf[i] = pb[i];
    if (t < 128) cnt[t] = 0;
    __syncthreads();
    for (int i = t; i < m; i += 512) atomicAdd(&cnt[ebuf[i] >> 24], 1);
    __syncthreads();
    int v = 0, val = 0;
    if (t < 128) { v = cnt[t]; val = v; cur[t] = val; }
    __syncthreads();
    for (int ofs = 1; ofs < 128; ofs <<= 1) {
        int add = (t < 128 && t >= ofs) ? cur[t - ofs] : 0;
        __syncthreads();
        if (t < 128) { val += add; cur[t] = val; }
        __syncthreads();
    }
    if (t < 128) {
        int node = b * 128 + t;
        if (node <= N_NODES) rp[node] = o + (val - v);
        cur[t] = val - v;
    }
    __syncthreads();
    for (int i = t; i < m; i += 512) {
        unsigned p = ebuf[i];
        int l = p >> 24;
        int pos = atomicAdd(&cur[l], 1);
        csr[o + pos] = (int)(p & 0xFFFFFFu);
    }
}

// ---------------------------------------------------------------------------
// Gather (+fused prev-layer BN+ReLU on loads) + MLP + BN partials.
// 8 threads per node, 2-row unroll (VGPR ~40, high occupancy), butterfly
// merge; subs 0-3 compute 5 output channels each; partials [2*HID][NBG].
// ---------------------------------------------------------------------------
template<int DIN, bool BN>
__global__ __launch_bounds__(256) void gather_mlp8(
        const float* __restrict__ h,
        const int* __restrict__ rp, const int* __restrict__ csr,
        const float* __restrict__ W,    // [DIN][HID]
        const float* __restrict__ bias,
        const float* __restrict__ ssin, // [2*HID] prev-layer scale/shift
        float* __restrict__ hpre,       // [N][HID]
        float* __restrict__ partials)   // [2*HID][NBG]
{
    __shared__ float sW[DIN * HID];
    __shared__ float sb[HID];
    __shared__ float sss[2 * HID];
    __shared__ float red[4][2 * HID];
    int t = threadIdx.x;
    for (int i = t; i < DIN * HID; i += 256) sW[i] = W[i];
    if (t < HID) sb[t] = bias[t];
    if constexpr (BN) { if (t < 2 * HID) sss[t] = ssin[t]; }
    __syncthreads();

    int node = blockIdx.x * 32 + (t >> 3);
    int sub  = t & 7;
    float u[DIN];
#pragma unroll
    for (int k = 0; k < DIN; k++) u[k] = 0.0f;

    auto acc4 = [&](float4 a, int q) {
        float v0 = a.x, v1 = a.y, v2 = a.z, v3 = a.w;
        if constexpr (BN) {
            v0 = fmaxf(fmaf(v0, sss[4*q+0], sss[HID+4*q+0]), 0.f);
            v1 = fmaxf(fmaf(v1, sss[4*q+1], sss[HID+4*q+1]), 0.f);
            v2 = fmaxf(fmaf(v2, sss[4*q+2], sss[HID+4*q+2]), 0.f);
            v3 = fmaxf(fmaf(v3, sss[4*q+3], sss[HID+4*q+3]), 0.f);
        }
        u[4*q] += v0; u[4*q+1] += v1; u[4*q+2] += v2; u[4*q+3] += v3;
    };

    if (node < N_NODES) {
        int e0 = rp[node], e1 = rp[node + 1];
        if (sub == 0) {   // self term
            if constexpr (DIN == 20) {
                const float4* hv = (const float4*)(h + (size_t)node * 20);
#pragma unroll
                for (int q = 0; q < 5; q++) acc4(hv[q], q);
            } else {
                const float2* hv = (const float2*)(h + (size_t)node * DIN);
#pragma unroll
                for (int q = 0; q < 5; q++) {
                    float2 a = hv[q];
                    u[2*q] += a.x; u[2*q+1] += a.y;
                }
            }
        }
        int e = e0 + sub;
        if constexpr (DIN == 20) {
            for (; e + 8 < e1; e += 16) {    // 2 rows in flight
                int s0 = csr[e], s1 = csr[e + 8];
                const float4* a0 = (const float4*)(h + (size_t)s0 * 20);
                const float4* a1 = (const float4*)(h + (size_t)s1 * 20);
                float4 r0[5], r1[5];
#pragma unroll
                for (int q = 0; q < 5; q++) r0[q] = a0[q];
#pragma unroll
                for (int q = 0; q < 5; q++) r1[q] = a1[q];
#pragma unroll
                for (int q = 0; q < 5; q++) { acc4(r0[q], q); acc4(r1[q], q); }
            }
            if (e < e1) {
                const float4* a0 = (const float4*)(h + (size_t)csr[e] * 20);
#pragma unroll
                for (int q = 0; q < 5; q++) acc4(a0[q], q);
            }
        } else {
            for (; e + 8 < e1; e += 16) {
                int s0 = csr[e], s1 = csr[e + 8];
                const float2* a0 = (const float2*)(h + (size_t)s0 * DIN);
                const float2* a1 = (const float2*)(h + (size_t)s1 * DIN);
                float2 r0[5], r1[5];
#pragma unroll
                for (int q = 0; q < 5; q++) r0[q] = a0[q];
#pragma unroll
                for (int q = 0; q < 5; q++) r1[q] = a1[q];
#pragma unroll
                for (int q = 0; q < 5; q++) {
                    u[2*q]   += r0[q].x + r1[q].x;
                    u[2*q+1] += r0[q].y + r1[q].y;
                }
            }
            if (e < e1) {
                const float2* a0 = (const float2*)(h + (size_t)csr[e] * DIN);
#pragma unroll
                for (int q = 0; q < 5; q++) {
                    float2 x0 = a0[q];
                    u[2*q] += x0.x; u[2*q+1] += x0.y;
                }
            }
        }
    }

    // merge 8 sub-accumulators
#pragma unroll
    for (int k = 0; k < DIN; k++) {
        u[k] += __shfl_xor(u[k], 1);
        u[k] += __shfl_xor(u[k], 2);
        u[k] += __shfl_xor(u[k], 4);
    }

    // MLP: subs 0-3 compute channels [sub*5, sub*5+5)
    const int c0 = (sub & 3) * 5;
    float out[5];
#pragma unroll
    for (int j = 0; j < 5; j++) out[j] = sb[c0 + j];
#pragma unroll
    for (int k = 0; k < DIN; k++) {
        float uk = u[k];
#pragma unroll
        for (int j = 0; j < 5; j++)
            out[j] = fmaf(uk, sW[k * HID + c0 + j], out[j]);
    }
    bool live = (node < N_NODES) && (sub < 4);
    if (live) {
        float* op = hpre + (size_t)node * HID + c0;
#pragma unroll
        for (int j = 0; j < 5; j++) op[j] = out[j];
    }

    // BN partials
    float msk = live ? 1.0f : 0.0f;
    float s1[5], s2[5];
#pragma unroll
    for (int j = 0; j < 5; j++) {
        float o = out[j] * msk;
        s1[j] = o; s2[j] = o * out[j];
    }
    for (int o = 8; o < 64; o <<= 1) {
#pragma unroll
        for (int j = 0; j < 5; j++) {
            s1[j] += __shfl_down(s1[j], o);
            s2[j] += __shfl_down(s2[j], o);
        }
    }
    int lane = t & 63, wave = t >> 6;
    if (lane < 4) {
#pragma unroll
        for (int j = 0; j < 5; j++) {
            red[wave][lane * 5 + j]       = s1[j];
            red[wave][HID + lane * 5 + j] = s2[j];
        }
    }
    __syncthreads();
    if (t < 2 * HID)
        partials[(size_t)t * NBG + blockIdx.x] =
            red[0][t] + red[1][t] + red[2][t] + red[3][t];
}

// ---------------------------------------------------------------------------
// BN prep: 20 blocks, block c reduces stat rows c and c+20 (coalesced), f64
// ---------------------------------------------------------------------------
__global__ __launch_bounds__(256) void bn_prep(const float* __restrict__ partials,
                                               const float* __restrict__ g,
                                               const float* __restrict__ beta,
                                               float* __restrict__ ss) {
    int c = blockIdx.x, t = threadIdx.x;
    double a1 = 0.0, a2 = 0.0;
    for (int i = t; i < NBG; i += 256) {
        a1 += (double)partials[(size_t)c * NBG + i];
        a2 += (double)partials[(size_t)(c + HID) * NBG + i];
    }
    for (int o = 32; o; o >>= 1) {
        a1 += __shfl_down(a1, o);
        a2 += __shfl_down(a2, o);
    }
    __shared__ double r1[4], r2[4];
    int lane = t & 63, wave = t >> 6;
    if (lane == 0) { r1[wave] = a1; r2[wave] = a2; }
    __syncthreads();
    if (t == 0) {
        double su = r1[0] + r1[1] + r1[2] + r1[3];
        double sq = r2[0] + r2[1] + r2[2] + r2[3];
        double mu  = su / (double)N_NODES;
        double var = sq / (double)N_NODES - mu * mu;
        float sc = g[c] * (float)(1.0 / sqrt(var + (double)BN_EPS));
        ss[c]       = sc;
        ss[HID + c] = beta[c] - (float)mu * sc;
    }
}

// ---------------------------------------------------------------------------
// graph_ptr from sorted batch (handles empty graphs)
// ---------------------------------------------------------------------------
__global__ void gptr_kernel(const int* __restrict__ batch, int* __restrict__ gptr) {
    int n = blockIdx.x * blockDim.x + threadIdx.x;
    if (n >= N_NODES) return;
    int g = batch[n];
    int gp = (n == 0) ? -1 : batch[n - 1];
    for (int q = gp + 1; q <= g; q++) gptr[q] = n;
    if (n == N_NODES - 1)
        for (int q = g + 1; q <= N_GRAPHS; q++) gptr[q] = N_NODES;
}

// ---------------------------------------------------------------------------
// Pool (+fused BN3+ReLU) + FC, block per graph
// ---------------------------------------------------------------------------
__global__ __launch_bounds__(256) void pool_fc(const float* __restrict__ h,
                                               const int* __restrict__ gptr,
                                               const float* __restrict__ ss,
                                               const float* __restrict__ fcW,
                                               const float* __restrict__ fcb,
                                               float* __restrict__ out) {
    __shared__ float red[12][HID];
    __shared__ float sss[2 * HID];
    __shared__ float pl[HID];
    int g = blockIdx.x, t = threadIdx.x;
    if (t < 2 * HID) sss[t] = ss[t];
    __syncthreads();
    int n0 = gptr[g], n1 = gptr[g + 1];
    if (t < 240) {
        int c = t % HID, grp = t / HID;
        float s = 0.0f;
        for (int n = n0 + grp; n < n1; n += 12) {
            float v = fmaf(h[(size_t)n * HID + c], sss[c], sss[HID + c]);
            s += v > 0.0f ? v : 0.0f;
        }
        red[grp][c] = s;
    }
    __syncthreads();
    if (t < HID) {
        float a = 0.0f;
#pragma unroll
        for (int q = 0; q < 12; q++) a += red[q][t];
        pl[t] = a;
    }
    __syncthreads();
    if (t < 2) {
        float o = fcb[t];
#pragma unroll
        for (int k = 0; k < HID; k++) o = fmaf(pl[k], fcW[k * 2 + t], o);
        out[g * 2 + t] = o;
    }
}

extern "C" void kernel_launch(void* const* d_in, const int* in_sizes, int n_in,
                              void* d_out, int out_size, void* d_ws, size_t ws_size,
                              hipStream_t stream) {
    const float* x     = (const float*)d_in[0];
    const int*   eidx  = (const int*)d_in[1];
    const int*   batch = (const int*)d_in[2];
    const float* W1 = (const float*)d_in[3];
    const float* b1 = (const float*)d_in[4];
    const float* g1 = (const float*)d_in[5];
    const float* be1 = (const float*)d_in[6];
    const float* W2 = (const float*)d_in[7];
    const float* b2 = (const float*)d_in[8];
    const float* g2 = (const float*)d_in[9];
    const float* be2 = (const float*)d_in[10];
    const float* W3 = (const float*)d_in[11];
    const float* b3 = (const float*)d_in[12];
    const float* g3 = (const float*)d_in[13];
    const float* be3 = (const float*)d_in[14];
    const float* fcW = (const float*)d_in[15];
    const float* fcb = (const float*)d_in[16];
    float* out = (float*)d_out;

    const int* src = eidx;
    const int* dst = eidx + N_EDGES;

    // workspace layout (bytes). packed (build-only, 14.4MB fixed-cap) aliases
    // hA/hB (16MB): build completes before any gather writes hA/hB.
    char* ws = (char*)d_ws;
    float* hA      = (float*)(ws + 0);               // 8,000,000
    float* hB      = (float*)(ws + 8000000);         // 8,000,000
    unsigned* packed = (unsigned*)(ws + 0);          // NB*CAP*4 = 14,411,776 (alias)
    int*   csr     = (int*)(ws + 16000000);          // 12,800,000
    int*   rp      = (int*)(ws + 28800000);          // 400,004
    int*   off     = (int*)(ws + 29200128);          // 3,132
    int*   bcur    = (int*)(ws + 29203328);          // 3,128
    float* partials= (float*)(ws + 29209728);        // 40*3125*4 = 500,000
    float* ss1     = (float*)(ws + 29709728);        // 160
    float* ss2     = (float*)(ws + 29709888);        // 160
    float* ss3     = (float*)(ws + 29710048);        // 160
    int*   gptr    = (int*)(ws + 29710208);          // 4,004

    const int BLK = 256;

    // ---- sorted node-exact CSR (built once, reused by all 3 layers) ----
    hipMemsetAsync(bcur, 0, NB * sizeof(int), stream);
    fill_direct<<<FB, FT, 0, stream>>>(src, dst, bcur, packed);
    scan_buckets<<<1, 1024, 0, stream>>>(bcur, off);
    sort_bucket<<<NB, 512, 0, stream>>>(packed, bcur, off, csr, rp);
    gptr_kernel<<<(N_NODES + BLK - 1) / BLK, BLK, 0, stream>>>(batch, gptr);

    // ---- layer 1 (DIN=10, no input BN) ----
    gather_mlp8<IN_DIM, false><<<NBG, BLK, 0, stream>>>(x, rp, csr, W1, b1, ss1, hA, partials);
    bn_prep<<<HID, BLK, 0, stream>>>(partials, g1, be1, ss1);

    // ---- layer 2 (DIN=20, fused BN1+ReLU on loads) ----
    gather_mlp8<HID, true><<<NBG, BLK, 0, stream>>>(hA, rp, csr, W2, b2, ss1, hB, partials);
    bn_prep<<<HID, BLK, 0, stream>>>(partials, g2, be2, ss2);

    // ---- layer 3 (DIN=20, fused BN2+ReLU on loads) ----
    gather_mlp8<HID, true><<<NBG, BLK, 0, stream>>>(hB, rp, csr, W3, b3, ss2, hA, partials);
    bn_prep<<<HID, BLK, 0, stream>>>(partials, g3, be3, ss3);

    // ---- pool (+BN3+ReLU) + FC ----
    pool_fc<<<N_GRAPHS, BLK, 0, stream>>>(hA, gptr, ss3, fcW, fcb, out);
}

// Round 8
// 317.107 us; speedup vs baseline: 1.1862x; 1.0730x over previous
//
#include <hip/hip_runtime.h>
#include <hip/hip_bf16.h>
#include <hip/hip_fp16.h>

#define N_NODES  100000
#define N_EDGES  3200000
#define N_GRAPHS 1000
#define IN_DIM   10
#define HID      20
#define BN_EPS   1e-5f

#define BSH   8                              // 256-node buckets
#define NB    ((N_NODES + 255) / 256)        // 391 buckets
#define CAP   9216                           // per-bucket capacity (mean 8184 + ~11 sigma)
#define FB    512                            // fill blocks
#define FCHUNK ((N_EDGES + FB - 1) / FB)     // 6250 edges/block
#define NBG   ((N_NODES + 31) / 32)          // 3125 gather blocks (32 nodes, 8 subs)
#define HS    24                             // fp16 row stride (halfs) = 48 B

// ---------------------------------------------------------------------------
// Fill into fixed-capacity 256-node buckets. Two passes over chunk; per-block
// LDS count, one global cursor reservation per bucket, dense run writes.
// packed = src | (dst&255)<<24 at packed[b*CAP + ...]
// ---------------------------------------------------------------------------
__global__ __launch_bounds__(512) void fill_direct(const int* __restrict__ src,
                                                   const int* __restrict__ dst,
                                                   int* __restrict__ bcur,
                                                   unsigned* __restrict__ packed) {
    __shared__ int cnt[NB];
    __shared__ int base[NB];
    int t = threadIdx.x;
    for (int i = t; i < NB; i += 512) cnt[i] = 0;
    __syncthreads();
    int e0 = blockIdx.x * FCHUNK;
    int e1 = min(e0 + FCHUNK, N_EDGES);
    for (int e = e0 + t; e < e1; e += 512)
        atomicAdd(&cnt[dst[e] >> BSH], 1);
    __syncthreads();
    for (int i = t; i < NB; i += 512) {
        int c = cnt[i];
        base[i] = c ? atomicAdd(&bcur[i], c) : 0;
        cnt[i] = 0;
    }
    __syncthreads();
    for (int e = e0 + t; e < e1; e += 512) {
        int d = dst[e];
        int b = d >> BSH;
        int r = atomicAdd(&cnt[b], 1);
        packed[(size_t)b * CAP + base[b] + r] =
            (unsigned)src[e] | ((unsigned)(d & 255) << 24);
    }
}

// ---------------------------------------------------------------------------
// Exclusive scan of bucket counts -> compact csr offsets
// ---------------------------------------------------------------------------
__global__ void scan_buckets(const int* __restrict__ bcur, int* __restrict__ off) {
    __shared__ int lds[512];
    int t = threadIdx.x;
    int v = (t < NB) ? bcur[t] : 0;
    int val = v;
    lds[t] = val; __syncthreads();
    for (int o = 1; o < 512; o <<= 1) {
        int a = (t >= o) ? lds[t - o] : 0;
        __syncthreads();
        val += a; lds[t] = val;
        __syncthreads();
    }
    if (t < NB) off[t] = val - v;
    if (t == 0) off[NB] = N_EDGES;
}

// ---------------------------------------------------------------------------
// Per-bucket counting sort by 8-bit local dst -> compact node-exact CSR + rp
// ---------------------------------------------------------------------------
__global__ __launch_bounds__(512) void sort_bucket(const unsigned* __restrict__ packed,
                                                   const int* __restrict__ bcnt,
                                                   const int* __restrict__ off,
                                                   int* __restrict__ csr,
                                                   int* __restrict__ rp) {
    __shared__ unsigned ebuf[CAP];     // 36,864 B
    __shared__ int cnt[256];
    __shared__ int cur[256];
    int b = blockIdx.x, t = threadIdx.x;
    int m = bcnt[b];
    int o = off[b];
    const unsigned* pb = packed + (size_t)b * CAP;
    for (int i = t; i < m; i += 512) ebuf[i] = pb[i];
    if (t < 256) cnt[t] = 0;
    __syncthreads();
    for (int i = t; i < m; i += 512) atomicAdd(&cnt[ebuf[i] >> 24], 1);
    __syncthreads();
    int v = 0, val = 0;
    if (t < 256) { v = cnt[t]; val = v; cur[t] = val; }
    __syncthreads();
    for (int ofs = 1; ofs < 256; ofs <<= 1) {
        int add = (t < 256 && t >= ofs) ? cur[t - ofs] : 0;
        __syncthreads();
        if (t < 256) { val += add; cur[t] = val; }
        __syncthreads();
    }
    if (t < 256) {
        int node = b * 256 + t;
        if (node <= N_NODES) rp[node] = o + (val - v);
        cur[t] = val - v;
    }
    __syncthreads();
    for (int i = t; i < m; i += 512) {
        unsigned p = ebuf[i];
        int l = p >> 24;
        int pos = atomicAdd(&cur[l], 1);
        csr[o + pos] = (int)(p & 0xFFFFFFu);
    }
}

// ---------------------------------------------------------------------------
// Gather (+fused prev-layer BN+ReLU) + MLP + BN partials; fp16 h storage.
// DIN==10: input = f32 x. DIN==20: input = fp16 rows, 48B stride.
// 8 threads/node, 2-row unroll; subs 0-3 compute 5 channels each; output
// repacked to fp16 rows via LDS (3 coalesced vector stores per node).
// ---------------------------------------------------------------------------
template<int DIN, bool BN>
__global__ __launch_bounds__(256) void gather_mlp8(
        const float* __restrict__ hf,    // f32 input (DIN==10)
        const __half* __restrict__ hh,   // fp16 input (DIN==20)
        const int* __restrict__ rp, const int* __restrict__ csr,
        const float* __restrict__ W,     // [DIN][HID]
        const float* __restrict__ bias,
        const float* __restrict__ ssin,  // [2*HID] prev-layer scale/shift
        __half* __restrict__ hout,       // [N][HS] fp16 rows
        float* __restrict__ partials)    // [2*HID][NBG]
{
    __shared__ float sW[DIN * HID];
    __shared__ float sb[HID];
    __shared__ float sss[2 * HID];
    __shared__ float red[4][2 * HID];
    __shared__ __half sh_h[32][HS];      // 1536 B output repack
    int t = threadIdx.x;
    for (int i = t; i < DIN * HID; i += 256) sW[i] = W[i];
    if (t < HID) sb[t] = bias[t];
    if constexpr (BN) { if (t < 2 * HID) sss[t] = ssin[t]; }
    __syncthreads();

    int node = blockIdx.x * 32 + (t >> 3);
    int sub  = t & 7;
    float u[DIN];
#pragma unroll
    for (int k = 0; k < DIN; k++) u[k] = 0.0f;

    // accumulate one fp16 row already staged in w[10] (half2 per word)
    auto accw = [&](const unsigned* w) {
#pragma unroll
        for (int q = 0; q < 10; q++) {
            float2 f = __half22float2(*(const __half2*)&w[q]);
            float v0 = f.x, v1 = f.y;
            if constexpr (BN) {
                v0 = fmaxf(fmaf(v0, sss[2*q+0], sss[HID+2*q+0]), 0.f);
                v1 = fmaxf(fmaf(v1, sss[2*q+1], sss[HID+2*q+1]), 0.f);
            }
            u[2*q] += v0; u[2*q+1] += v1;
        }
    };

    if (node < N_NODES) {
        int e0 = rp[node], e1 = rp[node + 1];
        if constexpr (DIN == 20) {
            if (sub == 0) {   // self term
                const __half* r = hh + (size_t)node * HS;
                unsigned w[10];
                uint4 A = *(const uint4*)r;
                uint4 B = *(const uint4*)(r + 8);
                uint2 C = *(const uint2*)(r + 16);
                w[0]=A.x; w[1]=A.y; w[2]=A.z; w[3]=A.w;
                w[4]=B.x; w[5]=B.y; w[6]=B.z; w[7]=B.w;
                w[8]=C.x; w[9]=C.y;
                accw(w);
            }
            int e = e0 + sub;
            for (; e + 8 < e1; e += 16) {    // 2 rows in flight
                int s0 = csr[e], s1 = csr[e + 8];
                const __half* r0 = hh + (size_t)s0 * HS;
                const __half* r1 = hh + (size_t)s1 * HS;
                uint4 A0 = *(const uint4*)r0;
                uint4 B0 = *(const uint4*)(r0 + 8);
                uint2 C0 = *(const uint2*)(r0 + 16);
                uint4 A1 = *(const uint4*)r1;
                uint4 B1 = *(const uint4*)(r1 + 8);
                uint2 C1 = *(const uint2*)(r1 + 16);
                unsigned w0[10] = {A0.x,A0.y,A0.z,A0.w,B0.x,B0.y,B0.z,B0.w,C0.x,C0.y};
                unsigned w1[10] = {A1.x,A1.y,A1.z,A1.w,B1.x,B1.y,B1.z,B1.w,C1.x,C1.y};
                accw(w0); accw(w1);
            }
            if (e < e1) {
                const __half* r0 = hh + (size_t)csr[e] * HS;
                uint4 A = *(const uint4*)r0;
                uint4 B = *(const uint4*)(r0 + 8);
                uint2 C = *(const uint2*)(r0 + 16);
                unsigned w[10] = {A.x,A.y,A.z,A.w,B.x,B.y,B.z,B.w,C.x,C.y};
                accw(w);
            }
        } else {
            if (sub == 0) {   // self term, f32 x
                const float2* hv = (const float2*)(hf + (size_t)node * DIN);
#pragma unroll
                for (int q = 0; q < 5; q++) {
                    float2 a = hv[q];
                    u[2*q] += a.x; u[2*q+1] += a.y;
                }
            }
            int e = e0 + sub;
            for (; e + 8 < e1; e += 16) {
                int s0 = csr[e], s1 = csr[e + 8];
                const float2* a0 = (const float2*)(hf + (size_t)s0 * DIN);
                const float2* a1 = (const float2*)(hf + (size_t)s1 * DIN);
                float2 r0[5], r1[5];
#pragma unroll
                for (int q = 0; q < 5; q++) r0[q] = a0[q];
#pragma unroll
                for (int q = 0; q < 5; q++) r1[q] = a1[q];
#pragma unroll
                for (int q = 0; q < 5; q++) {
                    u[2*q]   += r0[q].x + r1[q].x;
                    u[2*q+1] += r0[q].y + r1[q].y;
                }
            }
            if (e < e1) {
                const float2* a0 = (const float2*)(hf + (size_t)csr[e] * DIN);
#pragma unroll
                for (int q = 0; q < 5; q++) {
                    float2 x0 = a0[q];
                    u[2*q] += x0.x; u[2*q+1] += x0.y;
                }
            }
        }
    }

    // merge 8 sub-accumulators
#pragma unroll
    for (int k = 0; k < DIN; k++) {
        u[k] += __shfl_xor(u[k], 1);
        u[k] += __shfl_xor(u[k], 2);
        u[k] += __shfl_xor(u[k], 4);
    }

    // MLP: subs 0-3 compute channels [sub*5, sub*5+5)
    const int c0 = (sub & 3) * 5;
    float out[5];
#pragma unroll
    for (int j = 0; j < 5; j++) out[j] = sb[c0 + j];
#pragma unroll
    for (int k = 0; k < DIN; k++) {
        float uk = u[k];
#pragma unroll
        for (int j = 0; j < 5; j++)
            out[j] = fmaf(uk, sW[k * HID + c0 + j], out[j]);
    }
    bool live = (node < N_NODES) && (sub < 4);
    if (live) {
        int nl = t >> 3;
#pragma unroll
        for (int j = 0; j < 5; j++) sh_h[nl][c0 + j] = __float2half(out[j]);
    }

    // BN partials (from exact f32 values)
    float msk = live ? 1.0f : 0.0f;
    float s1[5], s2[5];
#pragma unroll
    for (int j = 0; j < 5; j++) {
        float o = out[j] * msk;
        s1[j] = o; s2[j] = o * out[j];
    }
    for (int o = 8; o < 64; o <<= 1) {
#pragma unroll
        for (int j = 0; j < 5; j++) {
            s1[j] += __shfl_down(s1[j], o);
            s2[j] += __shfl_down(s2[j], o);
        }
    }
    int lane = t & 63, wave = t >> 6;
    if (lane < 4) {
#pragma unroll
        for (int j = 0; j < 5; j++) {
            red[wave][lane * 5 + j]       = s1[j];
            red[wave][HID + lane * 5 + j] = s2[j];
        }
    }
    __syncthreads();
    // coalesced fp16 row store: 48B per node via 2x16B + 1x8B
    if (t < 32) {
        int n2 = blockIdx.x * 32 + t;
        if (n2 < N_NODES) {
            const uint4* sp = (const uint4*)&sh_h[t][0];
            uint4 a0 = sp[0], a1 = sp[1];
            uint2 a2 = ((const uint2*)sp)[4];
            uint4* gp = (uint4*)(hout + (size_t)n2 * HS);
            gp[0] = a0; gp[1] = a1;
            ((uint2*)gp)[4] = a2;
        }
    }
    if (t < 2 * HID)
        partials[(size_t)t * NBG + blockIdx.x] =
            red[0][t] + red[1][t] + red[2][t] + red[3][t];
}

// ---------------------------------------------------------------------------
// BN prep: 20 blocks, block c reduces stat rows c and c+20 (coalesced), f64
// ---------------------------------------------------------------------------
__global__ __launch_bounds__(256) void bn_prep(const float* __restrict__ partials,
                                               const float* __restrict__ g,
                                               const float* __restrict__ beta,
                                               float* __restrict__ ss) {
    int c = blockIdx.x, t = threadIdx.x;
    double a1 = 0.0, a2 = 0.0;
    for (int i = t; i < NBG; i += 256) {
        a1 += (double)partials[(size_t)c * NBG + i];
        a2 += (double)partials[(size_t)(c + HID) * NBG + i];
    }
    for (int o = 32; o; o >>= 1) {
        a1 += __shfl_down(a1, o);
        a2 += __shfl_down(a2, o);
    }
    __shared__ double r1[4], r2[4];
    int lane = t & 63, wave = t >> 6;
    if (lane == 0) { r1[wave] = a1; r2[wave] = a2; }
    __syncthreads();
    if (t == 0) {
        double su = r1[0] + r1[1] + r1[2] + r1[3];
        double sq = r2[0] + r2[1] + r2[2] + r2[3];
        double mu  = su / (double)N_NODES;
        double var = sq / (double)N_NODES - mu * mu;
        float sc = g[c] * (float)(1.0 / sqrt(var + (double)BN_EPS));
        ss[c]       = sc;
        ss[HID + c] = beta[c] - (float)mu * sc;
    }
}

// ---------------------------------------------------------------------------
// graph_ptr from sorted batch (handles empty graphs)
// ---------------------------------------------------------------------------
__global__ void gptr_kernel(const int* __restrict__ batch, int* __restrict__ gptr) {
    int n = blockIdx.x * blockDim.x + threadIdx.x;
    if (n >= N_NODES) return;
    int g = batch[n];
    int gp = (n == 0) ? -1 : batch[n - 1];
    for (int q = gp + 1; q <= g; q++) gptr[q] = n;
    if (n == N_NODES - 1)
        for (int q = g + 1; q <= N_GRAPHS; q++) gptr[q] = N_NODES;
}

// ---------------------------------------------------------------------------
// Pool (+fused BN3+ReLU, fp16 input) + FC, block per graph
// ---------------------------------------------------------------------------
__global__ __launch_bounds__(256) void pool_fc(const __half* __restrict__ h,
                                               const int* __restrict__ gptr,
                                               const float* __restrict__ ss,
                                               const float* __restrict__ fcW,
                                               const float* __restrict__ fcb,
                                               float* __restrict__ out) {
    __shared__ float red[12][HID];
    __shared__ float sss[2 * HID];
    __shared__ float pl[HID];
    int g = blockIdx.x, t = threadIdx.x;
    if (t < 2 * HID) sss[t] = ss[t];
    __syncthreads();
    int n0 = gptr[g], n1 = gptr[g + 1];
    if (t < 240) {
        int c = t % HID, grp = t / HID;
        float s = 0.0f;
        for (int n = n0 + grp; n < n1; n += 12) {
            float v = fmaf(__half2float(h[(size_t)n * HS + c]), sss[c], sss[HID + c]);
            s += v > 0.0f ? v : 0.0f;
        }
        red[grp][c] = s;
    }
    __syncthreads();
    if (t < HID) {
        float a = 0.0f;
#pragma unroll
        for (int q = 0; q < 12; q++) a += red[q][t];
        pl[t] = a;
    }
    __syncthreads();
    if (t < 2) {
        float o = fcb[t];
#pragma unroll
        for (int k = 0; k < HID; k++) o = fmaf(pl[k], fcW[k * 2 + t], o);
        out[g * 2 + t] = o;
    }
}

extern "C" void kernel_launch(void* const* d_in, const int* in_sizes, int n_in,
                              void* d_out, int out_size, void* d_ws, size_t ws_size,
                              hipStream_t stream) {
    const float* x     = (const float*)d_in[0];
    const int*   eidx  = (const int*)d_in[1];
    const int*   batch = (const int*)d_in[2];
    const float* W1 = (const float*)d_in[3];
    const float* b1 = (const float*)d_in[4];
    const float* g1 = (const float*)d_in[5];
    const float* be1 = (const float*)d_in[6];
    const float* W2 = (const float*)d_in[7];
    const float* b2 = (const float*)d_in[8];
    const float* g2 = (const float*)d_in[9];
    const float* be2 = (const float*)d_in[10];
    const float* W3 = (const float*)d_in[11];
    const float* b3 = (const float*)d_in[12];
    const float* g3 = (const float*)d_in[13];
    const float* be3 = (const float*)d_in[14];
    const float* fcW = (const float*)d_in[15];
    const float* fcb = (const float*)d_in[16];
    float* out = (float*)d_out;

    const int* src = eidx;
    const int* dst = eidx + N_EDGES;

    // workspace layout (bytes). packed (build-only, 14.42 MB fixed-cap)
    // aliases hA16/hB16 (9.6 MB): build completes before gathers write h.
    char* ws = (char*)d_ws;
    __half* hA16   = (__half*)(ws + 0);              // 100000*24*2 = 4,800,000
    __half* hB16   = (__half*)(ws + 4800000);        // 4,800,000
    unsigned* packed = (unsigned*)(ws + 0);          // NB*CAP*4 = 14,415,744 (alias)
    int*   csr     = (int*)(ws + 16000000);          // 12,800,000
    int*   rp      = (int*)(ws + 28800000);          // 400,004
    int*   off     = (int*)(ws + 29200128);          // 1,568
    int*   bcur    = (int*)(ws + 29203328);          // 1,564
    float* partials= (float*)(ws + 29209728);        // 40*3125*4 = 500,000
    float* ss1     = (float*)(ws + 29709728);        // 160
    float* ss2     = (float*)(ws + 29709888);        // 160
    float* ss3     = (float*)(ws + 29710048);        // 160
    int*   gptr    = (int*)(ws + 29710208);          // 4,004

    const int BLK = 256;

    // ---- sorted node-exact CSR (built once, reused by all 3 layers) ----
    hipMemsetAsync(bcur, 0, NB * sizeof(int), stream);
    fill_direct<<<FB, 512, 0, stream>>>(src, dst, bcur, packed);
    scan_buckets<<<1, 512, 0, stream>>>(bcur, off);
    sort_bucket<<<NB, 512, 0, stream>>>(packed, bcur, off, csr, rp);
    gptr_kernel<<<(N_NODES + BLK - 1) / BLK, BLK, 0, stream>>>(batch, gptr);

    // ---- layer 1 (DIN=10, f32 x input, no input BN) ----
    gather_mlp8<IN_DIM, false><<<NBG, BLK, 0, stream>>>(x, (const __half*)nullptr,
        rp, csr, W1, b1, ss1, hA16, partials);
    bn_prep<<<HID, BLK, 0, stream>>>(partials, g1, be1, ss1);

    // ---- layer 2 (DIN=20, fp16 input, fused BN1+ReLU) ----
    gather_mlp8<HID, true><<<NBG, BLK, 0, stream>>>((const float*)nullptr, hA16,
        rp, csr, W2, b2, ss1, hB16, partials);
    bn_prep<<<HID, BLK, 0, stream>>>(partials, g2, be2, ss2);

    // ---- layer 3 (DIN=20, fp16 input, fused BN2+ReLU) ----
    gather_mlp8<HID, true><<<NBG, BLK, 0, stream>>>((const float*)nullptr, hB16,
        rp, csr, W3, b3, ss2, hA16, partials);
    bn_prep<<<HID, BLK, 0, stream>>>(partials, g3, be3, ss3);

    // ---- pool (+BN3+ReLU) + FC ----
    pool_fc<<<N_GRAPHS, BLK, 0, stream>>>(hA16, gptr, ss3, fcW, fcb, out);
}